// Round 11
// baseline (121.967 us; speedup 1.0000x reference)
//
#include <hip/hip_runtime.h>
#include <math.h>

#define B 16
#define L 128
#define H 100
#define P 20
#define CH 210
#define EPSF 1e-8f

// workspace layout (float offsets): cos 2MB + cosT 2MB
#define OFF_COS   0u
#define OFF_COST  524288u

typedef __attribute__((ext_vector_type(8))) short bf16x8;
typedef __attribute__((ext_vector_type(4))) float f32x4;

__device__ inline unsigned short f2bf(float x) {   // RNE float->bf16 bits
    union { float f; unsigned u; } c; c.f = x;
    unsigned r = c.u + 0x7fffu + ((c.u >> 16) & 1u);
    return (unsigned short)(r >> 16);
}

// ================= dispatch 1: pair (672 blocks, 4 blocks/CU) =================
// k: b = k&15, dir = (k>>4)&1, p = k>>5 (p==20 -> unweighted cos, writes cos/cosT).
// Kernel boundary provides cross-XCD coherence for dispatch 2 (G16).
__global__ __launch_bounds__(256, 4) void pair_kernel(
    const float* __restrict__ ctx_p, const float* __restrict__ ctx_h,
    const float* __restrict__ params,
    float* __restrict__ cosbuf, float* __restrict__ cosT,
    float* __restrict__ out)
{
    __shared__ __align__(16) char smem[37888];
    const int k = blockIdx.x, t = threadIdx.x;
    const int b = k & 15, dir = (k >> 4) & 1, p = k >> 5;

    short* sB     = (short*)smem;                 // 32768 B frag (cg*4+kt)*64+lane
    float* colred = (float*)(smem + 32768);       // [kind2][wave4][col128]
    float* nlds   = (float*)(smem + 32768 + 4096);// [side2][row128]

    // stage B (ctx_h dir-half) into MFMA frag layout; zero-pad k>=100
    for (int e = t; e < 2048; e += 256) {
        int cgi = e >> 8, kt = (e >> 6) & 3, qq = (e >> 4) & 3, rl2 = e & 15;
        int row = cgi*16 + rl2, kb = kt*32 + qq*8;
        float v[8];
#pragma unroll
        for (int j = 0; j < 8; ++j) v[j] = 0.f;
        const float* src = ctx_h + (size_t)(b*L + row)*(2*H) + dir*H;
        if (kb < H)     { float4 f = *(const float4*)(src + kb);     v[0]=f.x; v[1]=f.y; v[2]=f.z; v[3]=f.w; }
        if (kb + 4 < H) { float4 f = *(const float4*)(src + kb + 4); v[4]=f.x; v[5]=f.y; v[6]=f.z; v[7]=f.w; }
        bf16x8 pk;
#pragma unroll
        for (int j = 0; j < 8; ++j) pk[j] = (short)f2bf(v[j]);
        *(bf16x8*)&sB[e*8] = pk;
    }

    const float* prow = params + ((size_t)(2 + dir)*P + p)*H;   // used only when p<20

    // A frags: global->reg direct, scaled by w^2_p
    const int w = t >> 6, lane = t & 63, q = lane >> 4, rl = lane & 15;
    bf16x8 af[2][4];
#pragma unroll
    for (int rgi = 0; rgi < 2; ++rgi) {
        int row = (w*2 + rgi)*16 + rl;
        const float* src = ctx_p + (size_t)(b*L + row)*(2*H) + dir*H;
#pragma unroll
        for (int kt = 0; kt < 4; ++kt) {
            int kb = kt*32 + q*8;
            float v[8];
#pragma unroll
            for (int j = 0; j < 8; ++j) v[j] = 0.f;
            if (p < P) {
                if (kb < H) {
                    float4 f = *(const float4*)(src + kb);
                    float4 wv = *(const float4*)(prow + kb);
                    v[0]=f.x*wv.x*wv.x; v[1]=f.y*wv.y*wv.y; v[2]=f.z*wv.z*wv.z; v[3]=f.w*wv.w*wv.w;
                }
                if (kb + 4 < H) {
                    float4 f = *(const float4*)(src + kb + 4);
                    float4 wv = *(const float4*)(prow + kb + 4);
                    v[4]=f.x*wv.x*wv.x; v[5]=f.y*wv.y*wv.y; v[6]=f.z*wv.z*wv.z; v[7]=f.w*wv.w*wv.w;
                }
            } else {
                if (kb < H)     { float4 f = *(const float4*)(src + kb);     v[0]=f.x; v[1]=f.y; v[2]=f.z; v[3]=f.w; }
                if (kb + 4 < H) { float4 f = *(const float4*)(src + kb + 4); v[4]=f.x; v[5]=f.y; v[6]=f.z; v[7]=f.w; }
            }
            bf16x8 pk;
#pragma unroll
            for (int j = 0; j < 8; ++j) pk[j] = (short)f2bf(v[j]);
            af[rgi][kt] = pk;
        }
    }

    // in-block weighted norms (fp32-exact)
    {
        const int r = t & 127, sd = t >> 7;
        const float* nrow = (sd ? ctx_h : ctx_p) + (size_t)(b*L + r)*(2*H) + dir*H;
        float n2 = 0.f;
        if (p < P) {
            for (int g = 0; g < 25; ++g) {
                float4 v = *(const float4*)(nrow + 4*g);
                float4 wv = *(const float4*)(prow + 4*g);
                n2 = fmaf(wv.x*wv.x, v.x*v.x, n2);
                n2 = fmaf(wv.y*wv.y, v.y*v.y, n2);
                n2 = fmaf(wv.z*wv.z, v.z*v.z, n2);
                n2 = fmaf(wv.w*wv.w, v.w*v.w, n2);
            }
        } else {
            for (int g = 0; g < 25; ++g) {
                float4 v = *(const float4*)(nrow + 4*g);
                n2 = fmaf(v.x, v.x, n2); n2 = fmaf(v.y, v.y, n2);
                n2 = fmaf(v.z, v.z, n2); n2 = fmaf(v.w, v.w, n2);
            }
        }
        nlds[sd*128 + r] = sqrtf(n2);
    }
    __syncthreads();

    f32x4 acc[2][8];
#pragma unroll
    for (int rgi = 0; rgi < 2; ++rgi)
#pragma unroll
        for (int cgi = 0; cgi < 8; ++cgi) acc[rgi][cgi] = (f32x4)0.f;
#pragma unroll
    for (int kt = 0; kt < 4; ++kt) {
#pragma unroll
        for (int cgi = 0; cgi < 8; ++cgi) {
            bf16x8 bfr = *(bf16x8*)&sB[((cgi*4 + kt)*64 + lane)*8];
            acc[0][cgi] = __builtin_amdgcn_mfma_f32_16x16x32_bf16(af[0][kt], bfr, acc[0][cgi], 0, 0, 0);
            acc[1][cgi] = __builtin_amdgcn_mfma_f32_16x16x32_bf16(af[1][kt], bfr, acc[1][cgi], 0, 0, 0);
        }
    }

    float na[2][4];
#pragma unroll
    for (int rgi = 0; rgi < 2; ++rgi)
#pragma unroll
        for (int r = 0; r < 4; ++r) na[rgi][r] = nlds[0*128 + (w*2 + rgi)*16 + q*4 + r];
    float nbv[8];
#pragma unroll
    for (int cgi = 0; cgi < 8; ++cgi) nbv[cgi] = nlds[1*128 + cgi*16 + rl];

    const bool iscos = (p == P);
    float* cosm  = cosbuf + (size_t)(dir*B + b)*16384;
    float* cosmT = cosT   + (size_t)(dir*B + b)*16384;

    int chmax, chmean;
    if (p < P) { chmax = (dir ? 86 : 46) + p; chmean = (dir ? 106 : 66) + p; }
    else       { chmax = dir*2;              chmean = dir*2 + 1; }

    float rowm[2][4], rows_[2][4], colm[8], cols_[8];
#pragma unroll
    for (int rgi = 0; rgi < 2; ++rgi)
#pragma unroll
        for (int r = 0; r < 4; ++r) { rowm[rgi][r] = -INFINITY; rows_[rgi][r] = 0.f; }
#pragma unroll
    for (int cgi = 0; cgi < 8; ++cgi) { colm[cgi] = -INFINITY; cols_[cgi] = 0.f; }

#pragma unroll
    for (int rgi = 0; rgi < 2; ++rgi) {
        int i0 = (w*2 + rgi)*16 + q*4;
#pragma unroll
        for (int cgi = 0; cgi < 8; ++cgi) {
            float m[4];
#pragma unroll
            for (int r = 0; r < 4; ++r) {
                float d = fmaxf(na[rgi][r]*nbv[cgi], EPSF);
                m[r] = acc[rgi][cgi][r] * __builtin_amdgcn_rcpf(d);
                rowm[rgi][r] = fmaxf(rowm[rgi][r], m[r]);
                rows_[rgi][r] += m[r];
            }
            float cM = fmaxf(fmaxf(m[0], m[1]), fmaxf(m[2], m[3]));
            colm[cgi] = fmaxf(colm[cgi], cM);
            cols_[cgi] += (m[0] + m[1]) + (m[2] + m[3]);
            if (iscos) {
                int j = cgi*16 + rl;
                float4 f4; f4.x = m[0]; f4.y = m[1]; f4.z = m[2]; f4.w = m[3];
                *(float4*)&cosmT[j*128 + i0] = f4;
#pragma unroll
                for (int r = 0; r < 4; ++r) cosm[(i0 + r)*128 + j] = m[r];
            }
        }
    }
#pragma unroll
    for (int rgi = 0; rgi < 2; ++rgi)
#pragma unroll
        for (int r = 0; r < 4; ++r) {
            float mx = rowm[rgi][r], sm = rows_[rgi][r];
#pragma unroll
            for (int d = 1; d < 16; d <<= 1) {
                mx = fmaxf(mx, __shfl_xor(mx, d));
                sm += __shfl_xor(sm, d);
            }
            if (rl == 0) {
                int i = (w*2 + rgi)*16 + q*4 + r;
                float* orow = out + (size_t)(b*L + i)*CH;
                orow[chmax] = mx; orow[chmean] = sm * (1.f/L);
            }
        }
#pragma unroll
    for (int cgi = 0; cgi < 8; ++cgi) {
        float mx = colm[cgi], sm = cols_[cgi];
        mx = fmaxf(mx, __shfl_xor(mx, 16)); sm += __shfl_xor(sm, 16);
        mx = fmaxf(mx, __shfl_xor(mx, 32)); sm += __shfl_xor(sm, 32);
        if (q == 0) {
            colred[(0*4 + w)*128 + cgi*16 + rl] = mx;
            colred[(1*4 + w)*128 + cgi*16 + rl] = sm;
        }
    }
    __syncthreads();
    {
        int c = t & 127, kind = t >> 7;
        float v0 = colred[(kind*4 + 0)*128 + c], v1 = colred[(kind*4 + 1)*128 + c];
        float v2 = colred[(kind*4 + 2)*128 + c], v3 = colred[(kind*4 + 3)*128 + c];
        float* oh = out + (size_t)B*L*CH + (size_t)(b*L + c)*CH;
        if (kind == 0) {
            oh[chmax] = fmaxf(fmaxf(v0, v1), fmaxf(v2, v3));
        } else {
            float sm = (v0 + v1) + (v2 + v3);
            oh[chmean] = sm * (1.f/L);
        }
    }
}

// ================= dispatch 2: att (512) + point (64), 4 blocks/CU =================
__global__ __launch_bounds__(256, 4) void attpoint_kernel(
    const float* __restrict__ ctx_p, const int* __restrict__ mask_p,
    const float* __restrict__ ctx_h, const int* __restrict__ mask_h,
    const float* __restrict__ params,
    const float* __restrict__ cosbuf, const float* __restrict__ cosT,
    float* __restrict__ out)
{
    __shared__ __align__(16) char smem[36512];
    const int k = blockIdx.x, t = threadIdx.x;

    if (k >= 512) {
        // ---- point task m0/1 (lastv inline, w^2 from params) ----
        const int idx = k - 512;
        const int b = idx & 15, side = (idx >> 4) & 1, m = idx >> 5;
        const int i = t & 127, half = t >> 7;
        const int chb = m ? 25 : 4;
        const float* opp = side ? ctx_p : ctx_h;
        const int* omask = side ? mask_p : mask_h;

        int last = 0;
        if (m == 0) {
            int* sm = (int*)smem;
            if (t < 128) sm[t] = omask[b*L + t];
            __syncthreads();
            for (int s = 64; s > 0; s >>= 1) {
                if (t < s) sm[t] += sm[t + s];
                __syncthreads();
            }
            last = sm[0] - 1;
            if (last < 0) last = 0;
            __syncthreads();   // sm region reused as red below
        }

        const float* v1p = (side ? ctx_h : ctx_p) + (size_t)(b*L + i)*(2*H) + m*H;
        const float* v2p = (m == 0) ? (opp + (size_t)(b*L + last)*(2*H))
                                    : (opp + (size_t)(b*L + 0)*(2*H) + H);

        float s11[21], s22[21], s12[21];
#pragma unroll
        for (int p = 0; p < 21; ++p) { s11[p] = 0.f; s22[p] = 0.f; s12[p] = 0.f; }
        const int g0 = half ? 13 : 0, g1 = half ? 25 : 13;
        for (int g = g0; g < g1; ++g) {
            float4 x = *(const float4*)(v1p + 4*g);
            float4 y = *(const float4*)(v2p + 4*g);
            float xx[4] = {x.x*x.x, x.y*x.y, x.z*x.z, x.w*x.w};
            float yy[4] = {y.x*y.x, y.y*y.y, y.z*y.z, y.w*y.w};
            float xy[4] = {x.x*y.x, x.y*y.y, x.z*y.z, x.w*y.w};
#pragma unroll
            for (int hh = 0; hh < 4; ++hh) {
                int h = 4*g + hh;
#pragma unroll
                for (int p = 0; p < 21; ++p) {
                    float w2;
                    if (p < P) { float w = params[((size_t)(m*P + p))*H + h]; w2 = w*w; }
                    else w2 = 1.f;
                    s11[p] = fmaf(w2, xx[hh], s11[p]);
                    s22[p] = fmaf(w2, yy[hh], s22[p]);
                    s12[p] = fmaf(w2, xy[hh], s12[p]);
                }
            }
        }
        float* red = (float*)smem;   // [3][21][128] = 32256 B
        if (half) {
#pragma unroll
            for (int p = 0; p < 21; ++p) {
                red[(0*21 + p)*128 + i] = s11[p];
                red[(1*21 + p)*128 + i] = s22[p];
                red[(2*21 + p)*128 + i] = s12[p];
            }
        }
        __syncthreads();
        if (!half) {
            float* orow = out + (size_t)side*B*L*CH + (size_t)(b*L + i)*CH;
#pragma unroll
            for (int p = 0; p < 21; ++p) {
                float a = s11[p] + red[(0*21 + p)*128 + i];
                float c = s22[p] + red[(1*21 + p)*128 + i];
                float d = s12[p] + red[(2*21 + p)*128 + i];
                float cv = d / (fmaxf(sqrtf(a), EPSF) * fmaxf(sqrtf(c), EPSF));
                orow[(p == P) ? chb : (chb + 1 + p)] = cv;
            }
        }
        return;
    }

    // ---- att task (b, side, dir, rc): fp32 two-pass j-staging ----
    {
        const int b = k & 15, side = (k >> 4) & 1, dir = (k >> 5) & 1, rc = k >> 6;
        const int r0 = rc*16;
        float* svf = (float*)smem;                         // [64][100] fp32, 25600 B
        float (*cvT)[16] = (float(*)[16])(smem + 25600);   // [128][16], 8192 B (ends 33792)
        float* denred = (float*)(smem + 36000);            // [8][16], 512 B (ends 36512)
        // overlay (valid after final compute barrier):
        float* attv = (float*)smem;                        // [2][16][100] 12800 B
        float* v1s  = (float*)(smem + 12800);              // [16][100] 6400 B
        float* w2l  = (float*)(smem + 19200);              // [2][21][100] 16800 B (ends 36000)

        const float* mat = (side ? cosbuf : cosT) + (size_t)(dir*B + b)*16384;
        const float* srcJ = side ? ctx_p : ctx_h;
        const float* srcI = side ? ctx_h : ctx_p;

        // stage svf pass 0 (rows 0..63)
        for (int e = t; e < 1600; e += 256) {
            int row = e / 25, g = e - row*25;
            *(float4*)&svf[row*100 + 4*g] =
                *(const float4*)(srcJ + (size_t)(b*L + row)*(2*H) + dir*H + 4*g);
        }
        for (int e = t; e < 2048; e += 256) {
            int s = e >> 4, r = e & 15;
            cvT[s][r] = mat[s*L + r0 + r];
        }
        __syncthreads();

        // den[r] = sum_s cvT[s][r] partials (read in overlay phase)
        if (t < 128) {
            int row = t & 15, grp = t >> 4;
            float s = 0.f;
            for (int ss = 0; ss < 16; ++ss) s += cvT[grp*16 + ss][row];
            denred[grp*16 + row] = s;
        }

        const int tr = t & 7, th = t >> 3;   // 2 rows x 4 h per thread, th<25 active
        float acc[2][4], amx[2][4];
#pragma unroll
        for (int rr = 0; rr < 2; ++rr)
#pragma unroll
            for (int qq = 0; qq < 4; ++qq) { acc[rr][qq] = 0.f; amx[rr][qq] = -INFINITY; }
        if (th < 25) {
            for (int s = 0; s < 64; ++s) {
                float2 c2 = *(const float2*)&cvT[s][2*tr];
                float4 v4 = *(const float4*)&svf[s*100 + 4*th];
                float cs[2] = {c2.x, c2.y};
                float vs[4] = {v4.x, v4.y, v4.z, v4.w};
#pragma unroll
                for (int rr = 0; rr < 2; ++rr)
#pragma unroll
                    for (int qq = 0; qq < 4; ++qq) {
                        float pr = cs[rr] * vs[qq];
                        acc[rr][qq] += pr;
                        amx[rr][qq] = fmaxf(amx[rr][qq], pr);
                    }
            }
        }
        __syncthreads();   // pass0 svf reads done -> restage rows 64..127

        for (int e = t; e < 1600; e += 256) {
            int row = e / 25, g = e - row*25;
            *(float4*)&svf[row*100 + 4*g] =
                *(const float4*)(srcJ + (size_t)(b*L + 64 + row)*(2*H) + dir*H + 4*g);
        }
        __syncthreads();

        if (th < 25) {
            for (int s = 0; s < 64; ++s) {
                float2 c2 = *(const float2*)&cvT[64 + s][2*tr];
                float4 v4 = *(const float4*)&svf[s*100 + 4*th];
                float cs[2] = {c2.x, c2.y};
                float vs[4] = {v4.x, v4.y, v4.z, v4.w};
#pragma unroll
                for (int rr = 0; rr < 2; ++rr)
#pragma unroll
                    for (int qq = 0; qq < 4; ++qq) {
                        float pr = cs[rr] * vs[qq];
                        acc[rr][qq] += pr;
                        amx[rr][qq] = fmaxf(amx[rr][qq], pr);
                    }
            }
        }
        __syncthreads();   // svf/cvT reads done -> overlay valid

        if (th < 25) {
#pragma unroll
            for (int rr = 0; rr < 2; ++rr) {
                int rloc = 2*tr + rr;
                float dsum = 0.f;
#pragma unroll
                for (int g = 0; g < 8; ++g) dsum += denred[g*16 + rloc];
                float inv = 1.f / fmaxf(dsum, EPSF);
#pragma unroll
                for (int qq = 0; qq < 4; ++qq) {
                    attv[0*1600 + rloc*100 + 4*th + qq] = acc[rr][qq] * inv;
                    attv[1*1600 + rloc*100 + 4*th + qq] = amx[rr][qq];
                }
            }
        }
        for (int e = t; e < 400; e += 256) {
            int row = e / 25, g = e - row*25;
            *(float4*)&v1s[row*100 + 4*g] =
                *(const float4*)(srcI + (size_t)(b*L + r0 + row)*(2*H) + dir*H + 4*g);
        }
        // w^2: kind0 (mean) -> params[4+dir], kind1 (max) -> params[6+dir]; p==20 -> 1
        for (int e = t; e < 4200; e += 256) {
            int kind = e >= 2100 ? 1 : 0, r = e - kind*2100;
            int p = r / 100, h = r - p*100;
            float v = 1.f;
            if (p < P) {
                float w = params[((size_t)((4 + kind*2 + dir)*P + p))*H + h];
                v = w*w;
            }
            w2l[kind*2100 + p*100 + h] = v;
        }
        __syncthreads();

        // phase C: 32 tasks (kind2 x row16) x 8 lanes; lane owns p in {tt, tt+8, tt+16}
        {
            const int task = t >> 3, tt = t & 7;
            const int kind = task >> 4, row = task & 15;
            const float* av  = attv + kind*1600 + row*100;
            const float* v1r = v1s + row*100;
            const float* wk  = w2l + kind*2100;
            const int p0 = tt, p1 = tt + 8, p2 = tt + 16;   // p2 valid iff tt<5

            float s11[3], s22[3], s12[3];
#pragma unroll
            for (int j = 0; j < 3; ++j) { s11[j] = 0.f; s22[j] = 0.f; s12[j] = 0.f; }
            for (int h = 0; h < H; ++h) {
                float a = v1r[h], c = av[h];
                float xx = a*a, yy = c*c, xy = a*c;
                float w0 = wk[p0*100 + h];
                float w1 = wk[p1*100 + h];
                float w2 = wk[p2*100 + h];   // garbage for tt>=5, never written out
                s11[0] = fmaf(w0, xx, s11[0]); s22[0] = fmaf(w0, yy, s22[0]); s12[0] = fmaf(w0, xy, s12[0]);
                s11[1] = fmaf(w1, xx, s11[1]); s22[1] = fmaf(w1, yy, s22[1]); s12[1] = fmaf(w1, xy, s12[1]);
                s11[2] = fmaf(w2, xx, s11[2]); s22[2] = fmaf(w2, yy, s22[2]); s12[2] = fmaf(w2, xy, s12[2]);
            }
            int chb = kind ? (dir ? 189 : 168) : (dir ? 147 : 126);
            float* orow = out + (size_t)side*B*L*CH + (size_t)(b*L + r0 + row)*CH;
            int pown[3] = {p0, p1, p2};
#pragma unroll
            for (int j = 0; j < 3; ++j) {
                int p = pown[j];
                if (p < 21) {
                    float cv = s12[j] / (fmaxf(sqrtf(s11[j]), EPSF) * fmaxf(sqrtf(s22[j]), EPSF));
                    orow[(p == P) ? chb : (chb + 1 + p)] = cv;
                }
            }
        }
    }
}

extern "C" void kernel_launch(void* const* d_in, const int* in_sizes, int n_in,
                              void* d_out, int out_size, void* d_ws, size_t ws_size,
                              hipStream_t stream) {
    const float* ctx_p  = (const float*)d_in[0];
    const int*   mask_p = (const int*)d_in[1];
    const float* ctx_h  = (const float*)d_in[2];
    const int*   mask_h = (const int*)d_in[3];
    const float* params = (const float*)d_in[4];
    float* out = (float*)d_out;

    float* ws = (float*)d_ws;
    float* cosbuf = ws + OFF_COS;
    float* cosT   = ws + OFF_COST;

    pair_kernel    <<<dim3(672), 256, 0, stream>>>(ctx_p, ctx_h, params,
                                                   cosbuf, cosT, out);
    attpoint_kernel<<<dim3(576), 256, 0, stream>>>(ctx_p, mask_p, ctx_h, mask_h, params,
                                                   cosbuf, cosT, out);
}